// Round 13
// baseline (4321.004 us; speedup 1.0000x reference)
//
#include <hip/hip_runtime.h>
#include <hip/hip_bf16.h>

#define VOCAB  32000
#define DIM    1024
#define NLAYER 4
#define NB     8
#define SEQ    512

#define NGROUP       4
#define GBLKS        64                    // blocks per layer-group
#define SCAN_BLOCKS  (NGROUP * GBLKS)      // 256
#define SCAN_THREADS 512                   // 8 waves, role-split
#define ROWH         2056                  // act row stride (2048 + 8 pad halves)

typedef __attribute__((ext_vector_type(8))) short          bf16x8;
typedef __attribute__((ext_vector_type(4))) float          f32x4;
typedef __attribute__((ext_vector_type(8))) unsigned short u16x8;
typedef __attribute__((ext_vector_type(8))) _Float16       h8f;

__device__ __forceinline__ u16x8 cvt8_bf16(const float* p) {
    float4 f0 = *(const float4*)p;
    float4 f1 = *(const float4*)(p + 4);
    union { __hip_bfloat16 h[8]; u16x8 v; } u;
    u.h[0] = __float2bfloat16(f0.x); u.h[1] = __float2bfloat16(f0.y);
    u.h[2] = __float2bfloat16(f0.z); u.h[3] = __float2bfloat16(f0.w);
    u.h[4] = __float2bfloat16(f1.x); u.h[5] = __float2bfloat16(f1.y);
    u.h[6] = __float2bfloat16(f1.z); u.h[7] = __float2bfloat16(f1.w);
    return u.v;
}

__device__ __forceinline__ h8f pack8(f32x4 a, f32x4 b) {
    h8f o;
    o[0] = (_Float16)a[0]; o[1] = (_Float16)a[1];
    o[2] = (_Float16)a[2]; o[3] = (_Float16)a[3];
    o[4] = (_Float16)b[0]; o[5] = (_Float16)b[1];
    o[6] = (_Float16)b[2]; o[7] = (_Float16)b[3];
    return o;
}

// ---- coherence-point (L3) loads/stores: bypass per-XCD L2 (no fences needed)
__device__ __forceinline__ void ld4v(f32x4& d, const float* p) {
    asm volatile("global_load_dwordx4 %0, %1, off sc0 sc1"
                 : "=&v"(d) : "v"(p));
}
__device__ __forceinline__ void st1v(float* p, float v) {
    asm volatile("global_store_dword %0, %1, off sc0 sc1"
                 :: "v"(p), "v"(v) : "memory");
}
__device__ __forceinline__ void vmwait0() {
    asm volatile("s_waitcnt vmcnt(0)" ::: "memory");
}

// ---------------------------------------------------------------------------
__global__ void bar_init_kernel(unsigned* __restrict__ bar) {
    bar[threadIdx.x]        = 0u;
    bar[threadIdx.x + 1024] = 0u;
    bar[threadIdx.x + 2048] = 0u;
    bar[threadIdx.x + 3072] = 0u;   // 4096 words
}

// ---------------------------------------------------------------------------
// Fence-free slot barrier, ALL-WAVE polling: entry __syncthreads drains data
// stores; tid0 release-stores its slot; then EVERY wave polls all 64 slots
// independently and proceeds as soon as it detects completion (no exit
// syncthreads — per-wave decoupling hides detection skew).
// ---------------------------------------------------------------------------
__device__ __forceinline__ void slot_bar(unsigned* __restrict__ slots, int bkg,
                                         unsigned seq, bool& dead) {
    __syncthreads();
    if (threadIdx.x == 0)
        __hip_atomic_store(&slots[bkg * 8], seq, __ATOMIC_RELAXED,
                           __HIP_MEMORY_SCOPE_AGENT);
    if (!dead) {
        const int sl = (threadIdx.x & 63) * 8;
        unsigned guard = 0;
        for (;;) {
            unsigned v = __hip_atomic_load(&slots[sl], __ATOMIC_RELAXED,
                                           __HIP_MEMORY_SCOPE_AGENT);
            if (__all((int)(v >= seq))) break;
            __builtin_amdgcn_s_sleep(1);
            if (++guard > (1u << 16)) { dead = true; break; }
        }
    }
}

// ---------------------------------------------------------------------------
// MFMA layer-pipelined persistent-weight GRU scan (round-12 compute).
// Wave roles: w0-3 z+r K-quarters; w4-5 candA/candB K-halves; w6 z-combine +
// update; w7 r-combine. All-wave barriers/gates (no exit syncthreads).
// ---------------------------------------------------------------------------
__global__ void __launch_bounds__(SCAN_THREADS)
__attribute__((amdgpu_waves_per_eu(2, 2)))
gru_scan(
    const int*   __restrict__ ids,     // [NB][SEQ]
    const float* __restrict__ embW,    // [VOCAB][DIM]
    const float* __restrict__ hstart,  // [NLAYER][DIM]
    const float* __restrict__ gW,      // [NLAYER][2*DIM][2*DIM]
    const float* __restrict__ gB,      // [NLAYER][2*DIM]
    const float* __restrict__ cW,      // [NLAYER][DIM][2*DIM]
    const float* __restrict__ cB,      // [NLAYER][DIM]
    float* __restrict__ hbuf,          // [4][NLAYER][NB][DIM]
    float* __restrict__ rbuf,          // [NGROUP][NB][DIM]
    float* __restrict__ ysf,           // [NB][SEQ][DIM] fp32
    unsigned* __restrict__ bar)
{
    __shared__ _Float16 act[NB][ROWH];      // 32,896 B
    __shared__ float pz[4][4][64];          // z partials  [wv][reg][lane]
    __shared__ float pr[4][4][64];          // r partials
    __shared__ float pc[2][4][64];          // candA partials
    __shared__ float pcb[2][4][64];         // candB partials

    const int tid   = threadIdx.x;
    const int lane  = tid & 63;
    const int wv    = tid >> 6;               // 0..7
    const int l15   = lane & 15;
    const int lgq   = lane >> 4;              // 0..3
    const int bcol  = l15 & 7;                // batch (cols 8..15 dup 0..7)
    const int g     = blockIdx.x >> 6;        // layer group
    const int bkg   = blockIdx.x & (GBLKS-1);
    const int jbase = bkg * 16;
    const int jrow  = jbase + l15;            // this lane's A row

    // ---- persistent A-fragment weights (pinned; live in unified VGPR/AGPR) ----
    h8f Wa[16], Wb[16];
    if (wv < 4) {                // z (Wa) + r (Wb), K-quarter
        const int kb = wv * 512;
        const float* wzp = gW + ((size_t)g * 2048 + jrow) * 2048;
        const float* wrp = gW + ((size_t)g * 2048 + 1024 + jrow) * 2048;
        #pragma unroll
        for (int kc = 0; kc < 16; ++kc) {
            const int k0 = kb + kc * 32 + lgq * 8;
            Wa[kc] = pack8(*(const f32x4*)(wzp + k0), *(const f32x4*)(wzp + k0 + 4));
            Wb[kc] = pack8(*(const f32x4*)(wrp + k0), *(const f32x4*)(wrp + k0 + 4));
        }
        #pragma unroll
        for (int kc = 0; kc < 16; ++kc) {
            asm volatile("" : "+v"(Wa[kc]));
            asm volatile("" : "+v"(Wb[kc]));
        }
    } else if (wv < 6) {         // candA (Wa, x-half) + candB (Wb, rh-half)
        const int kb = (wv - 4) * 512;
        const float* wcp = cW + ((size_t)g * 1024 + jrow) * 2048;
        #pragma unroll
        for (int kc = 0; kc < 16; ++kc) {
            const int k0 = kb + kc * 32 + lgq * 8;
            Wa[kc] = pack8(*(const f32x4*)(wcp + k0), *(const f32x4*)(wcp + k0 + 4));
            Wb[kc] = pack8(*(const f32x4*)(wcp + 1024 + k0), *(const f32x4*)(wcp + 1024 + k0 + 4));
        }
        #pragma unroll
        for (int kc = 0; kc < 16; ++kc) {
            asm volatile("" : "+v"(Wa[kc]));
            asm volatile("" : "+v"(Wb[kc]));
        }
    }

    float bz4[4], br4[4], cb4[4], hold[4], zreg[4];
    if (wv == 6) {
        #pragma unroll
        for (int r = 0; r < 4; ++r) {
            const int j = jbase + lgq * 4 + r;
            bz4[r]  = gB[g * 2048 + j];
            cb4[r]  = cB[g * 1024 + j];
            hold[r] = hstart[g * 1024 + j];
        }
    }
    if (wv == 7) {
        #pragma unroll
        for (int r = 0; r < 4; ++r)
            br4[r] = gB[g * 2048 + 1024 + jbase + lgq * 4 + r];
    }

    bool dead = false;
    unsigned* slots1g = bar + g * 512;
    unsigned* slots2g = bar + 2048 + g * 512;
    unsigned* s2prev  = (g > 0)          ? bar + 2048 + (g - 1) * 512 : nullptr;
    unsigned* s1next  = (g < NGROUP - 1) ? bar + (g + 1) * 512        : nullptr;
    float* rbufg = rbuf + (size_t)g * NB * DIM;

    // init own layer h(-1) into ring slot 3
    if (tid < 128) {
        int e = bkg * 128 + tid;
        st1v(&hbuf[((size_t)3 * NLAYER + g) * NB * DIM + e],
             hstart[g * DIM + (e & (DIM - 1))]);
    }
    slot_bar(slots2g, bkg, 1u, dead);

    for (int t = 0; t < SEQ; ++t) {
        const int so = (t + 3) & 3;
        const int sw = t & 3;
        const float* hsrc = hbuf + ((size_t)so * NLAYER + g) * NB * DIM;
        float*       hdst = hbuf + ((size_t)sw * NLAYER + g) * NB * DIM;

        // ---- peer gates: all-wave polling, no trailing syncthreads ----
        {
            const unsigned need_a = (g > 0) ? (unsigned)(t + 2) : 0u;
            const unsigned need_b = (g < NGROUP - 1 && t >= 4) ? (unsigned)(t - 3) : 0u;
            if (!dead && (need_a | need_b)) {
                const int sl = lane * 8;
                unsigned guard = 0;
                for (;;) {
                    bool ok = true;
                    if (need_a)
                        ok &= (__hip_atomic_load(&s2prev[sl], __ATOMIC_RELAXED,
                                                 __HIP_MEMORY_SCOPE_AGENT) >= need_a);
                    if (need_b)
                        ok &= (__hip_atomic_load(&s1next[sl], __ATOMIC_RELAXED,
                                                 __HIP_MEMORY_SCOPE_AGENT) >= need_b);
                    if (__all((int)ok)) break;
                    __builtin_amdgcn_s_sleep(1);
                    if (++guard > (1u << 16)) { dead = true; break; }
                }
            }
        }

        // ---- stage x -> act[.][0:1024), h_old -> act[.][1024:2048) fp16 ----
        {
            const int ub = tid & 127;        // 0..127 (8-half unit)
            const int b0 = tid >> 7;         // 0..3 (also stages b0+4)
            f32x4 xv0, xv1, xv2, xv3, hv0, hv1, hv2, hv3;
            if (g == 0) {
                const float* s0 = embW + (size_t)ids[b0 * SEQ + t] * DIM + ub * 8;
                const float* s1 = embW + (size_t)ids[(b0 + 4) * SEQ + t] * DIM + ub * 8;
                xv0 = *(const f32x4*)s0; xv1 = *(const f32x4*)(s0 + 4);
                xv2 = *(const f32x4*)s1; xv3 = *(const f32x4*)(s1 + 4);
            } else {
                const float* src = hbuf + ((size_t)sw * NLAYER + (g - 1)) * NB * DIM;
                ld4v(xv0, src + b0 * DIM + ub * 8);
                ld4v(xv1, src + b0 * DIM + ub * 8 + 4);
                ld4v(xv2, src + (b0 + 4) * DIM + ub * 8);
                ld4v(xv3, src + (b0 + 4) * DIM + ub * 8 + 4);
            }
            ld4v(hv0, hsrc + b0 * DIM + ub * 8);
            ld4v(hv1, hsrc + b0 * DIM + ub * 8 + 4);
            ld4v(hv2, hsrc + (b0 + 4) * DIM + ub * 8);
            ld4v(hv3, hsrc + (b0 + 4) * DIM + ub * 8 + 4);
            vmwait0();
            asm volatile("" : "+v"(xv0), "+v"(xv1), "+v"(xv2), "+v"(xv3),
                             "+v"(hv0), "+v"(hv1), "+v"(hv2), "+v"(hv3));
            *(h8f*)&act[b0][ub * 8]            = pack8(xv0, xv1);
            *(h8f*)&act[b0 + 4][ub * 8]        = pack8(xv2, xv3);
            *(h8f*)&act[b0][1024 + ub * 8]     = pack8(hv0, hv1);
            *(h8f*)&act[b0 + 4][1024 + ub * 8] = pack8(hv2, hv3);
        }
        __syncthreads();

        // ---- Phase A: MFMA dots ----
        if (wv < 6) {
            const int kb2 = (wv < 4) ? wv * 512 : (wv - 4) * 512;
            f32x4 accA = {0.f, 0.f, 0.f, 0.f};
            f32x4 accB = {0.f, 0.f, 0.f, 0.f};
            #pragma unroll
            for (int kc = 0; kc < 16; ++kc) {
                const h8f bf = *(const h8f*)&act[bcol][kb2 + kc * 32 + lgq * 8];
                accA = __builtin_amdgcn_mfma_f32_16x16x32_f16(Wa[kc], bf, accA, 0, 0, 0);
                if (wv < 4)
                    accB = __builtin_amdgcn_mfma_f32_16x16x32_f16(Wb[kc], bf, accB, 0, 0, 0);
            }
            if (wv < 4) {
                #pragma unroll
                for (int r = 0; r < 4; ++r) {
                    pz[wv][r][lane] = accA[r];
                    pr[wv][r][lane] = accB[r];
                }
            } else {
                #pragma unroll
                for (int r = 0; r < 4; ++r) pc[wv - 4][r][lane] = accA[r];
            }
        }
        __syncthreads();

        // ---- combine: z (w6, kept in regs) and r (w7 -> rbuf sc1) ----
        if (wv == 6) {
            #pragma unroll
            for (int r = 0; r < 4; ++r) {
                const float s = pz[0][r][lane] + pz[1][r][lane]
                              + pz[2][r][lane] + pz[3][r][lane] + bz4[r];
                zreg[r] = 1.f / (1.f + expf(-s));
            }
        }
        if (wv == 7) {
            #pragma unroll
            for (int r = 0; r < 4; ++r) {
                const float s = pr[0][r][lane] + pr[1][r][lane]
                              + pr[2][r][lane] + pr[3][r][lane] + br4[r];
                const float rg = 1.f / (1.f + expf(-s));
                if (l15 < 8)
                    st1v(rbufg + bcol * DIM + jbase + lgq * 4 + r, rg);
            }
        }
        // bar1: r published / xin consumed
        slot_bar(slots1g, bkg, (unsigned)(t + 1), dead);

        // ---- stage rh = r * h_old into act x-half ----
        {
            const int ub = tid & 127;
            const int b0 = tid >> 7;
            f32x4 rv0, rv1, rv2, rv3;
            ld4v(rv0, rbufg + b0 * DIM + ub * 8);
            ld4v(rv1, rbufg + b0 * DIM + ub * 8 + 4);
            ld4v(rv2, rbufg + (b0 + 4) * DIM + ub * 8);
            ld4v(rv3, rbufg + (b0 + 4) * DIM + ub * 8 + 4);
            h8f hh0 = *(const h8f*)&act[b0][1024 + ub * 8];
            h8f hh1 = *(const h8f*)&act[b0 + 4][1024 + ub * 8];
            vmwait0();
            asm volatile("" : "+v"(rv0), "+v"(rv1), "+v"(rv2), "+v"(rv3));
            h8f o0, o1;
            #pragma unroll
            for (int i = 0; i < 4; ++i) {
                o0[i]     = (_Float16)((float)hh0[i]     * rv0[i]);
                o0[i + 4] = (_Float16)((float)hh0[i + 4] * rv1[i]);
                o1[i]     = (_Float16)((float)hh1[i]     * rv2[i]);
                o1[i + 4] = (_Float16)((float)hh1[i + 4] * rv3[i]);
            }
            *(h8f*)&act[b0][ub * 8]     = o0;
            *(h8f*)&act[b0 + 4][ub * 8] = o1;
        }
        __syncthreads();

        // ---- Phase B: candB MFMA over rh ----
        if (wv == 4 || wv == 5) {
            const int kb2 = (wv - 4) * 512;
            f32x4 acc = {0.f, 0.f, 0.f, 0.f};
            #pragma unroll
            for (int kc = 0; kc < 16; ++kc) {
                const h8f bf = *(const h8f*)&act[bcol][kb2 + kc * 32 + lgq * 8];
                acc = __builtin_amdgcn_mfma_f32_16x16x32_f16(Wb[kc], bf, acc, 0, 0, 0);
            }
            #pragma unroll
            for (int r = 0; r < 4; ++r) pcb[wv - 4][r][lane] = acc[r];
        }
        __syncthreads();

        // ---- update (w6): cand = tanh(cA+cB+b), h = z*h + (1-z)*cand ----
        if (wv == 6) {
            #pragma unroll
            for (int r = 0; r < 4; ++r) {
                const float cand = tanhf(pc[0][r][lane] + pc[1][r][lane]
                                         + pcb[0][r][lane] + pcb[1][r][lane] + cb4[r]);
                const float hn = zreg[r] * hold[r] + (1.f - zreg[r]) * cand;
                hold[r] = hn;
                if (l15 < 8) {
                    const int j = jbase + lgq * 4 + r;
                    st1v(hdst + bcol * DIM + j, hn);
                    if (g == NGROUP - 1)
                        ysf[((size_t)bcol * SEQ + t) * DIM + j] = hn;
                }
            }
        }
        // bar2: h(t) published
        slot_bar(slots2g, bkg, (unsigned)(t + 2), dead);
    }

    if (dead && tid == 0)
        ysf[blockIdx.x] = 1.0e8f;   // unmistakable failure sentinel
}

// ---------------------------------------------------------------------------
// Logits GEMM (unchanged): C[m][n] = sum_k ys[m][k] * outW[n][k]
// ---------------------------------------------------------------------------
#define BM 128
#define BN 128
#define BK 64

__global__ void __launch_bounds__(256) out_gemm(
    const float* __restrict__ A,   // [4096][1024]  fp32
    const float* __restrict__ B,   // [32000][1024] fp32
    float* __restrict__ C)         // [4096][32000]
{
    __shared__ __hip_bfloat16 At[BM][BK + 8];
    __shared__ __hip_bfloat16 Bt[BN][BK + 8];

    const int tid  = threadIdx.x;
    const int lane = tid & 63;
    const int wv   = tid >> 6;
    const int wm   = wv >> 1, wn = wv & 1;
    const int m0   = blockIdx.y * BM;
    const int n0   = blockIdx.x * BN;

    f32x4 acc[4][4];
    #pragma unroll
    for (int i = 0; i < 4; ++i)
        #pragma unroll
        for (int jj = 0; jj < 4; ++jj)
            acc[i][jj] = (f32x4){0.f, 0.f, 0.f, 0.f};

    const int srow = tid >> 3;           // 0..31
    const int scol = (tid & 7) * 8;      // 0..56
    const int l15  = lane & 15;
    const int l4   = lane >> 4;

    for (int kt = 0; kt < DIM / BK; ++kt) {
        const int k0 = kt * BK;
        #pragma unroll
        for (int rnd = 0; rnd < 4; ++rnd) {
            const int row = rnd * 32 + srow;
            *(u16x8*)&At[row][scol] =
                cvt8_bf16(&A[(size_t)(m0 + row) * DIM + k0 + scol]);
            *(u16x8*)&Bt[row][scol] =
                cvt8_bf16(&B[(size_t)(n0 + row) * DIM + k0 + scol]);
        }
        __syncthreads();
        #pragma unroll
        for (int ks = 0; ks < 2; ++ks) {
            bf16x8 av[4], bv[4];
            #pragma unroll
            for (int i = 0; i < 4; ++i) {
                av[i] = *(const bf16x8*)&At[wm * 64 + i * 16 + l15][ks * 32 + l4 * 8];
                bv[i] = *(const bf16x8*)&Bt[wn * 64 + i * 16 + l15][ks * 32 + l4 * 8];
            }
            #pragma unroll
            for (int i = 0; i < 4; ++i)
                #pragma unroll
                for (int jj = 0; jj < 4; ++jj)
                    acc[i][jj] = __builtin_amdgcn_mfma_f32_16x16x32_bf16(
                        av[i], bv[jj], acc[i][jj], 0, 0, 0);
        }
        __syncthreads();
    }

    const int rq = l4 * 4;
    #pragma unroll
    for (int i = 0; i < 4; ++i) {
        const int rbase = m0 + wm * 64 + i * 16 + rq;
        #pragma unroll
        for (int jj = 0; jj < 4; ++jj) {
            const int col = n0 + wn * 64 + jj * 16 + l15;
            #pragma unroll
            for (int r2 = 0; r2 < 4; ++r2)
                C[(size_t)(rbase + r2) * VOCAB + col] = acc[i][jj][r2];
        }
    }
}

// ---------------------------------------------------------------------------
extern "C" void kernel_launch(void* const* d_in, const int* in_sizes, int n_in,
                              void* d_out, int out_size, void* d_ws, size_t ws_size,
                              hipStream_t stream)
{
    (void)in_sizes; (void)n_in; (void)out_size; (void)ws_size;
    const int*   ids  = (const int*)  d_in[0];
    const float* embW = (const float*)d_in[1];
    const float* hst  = (const float*)d_in[2];
    const float* gW   = (const float*)d_in[3];
    const float* gB   = (const float*)d_in[4];
    const float* cW   = (const float*)d_in[5];
    const float* cB   = (const float*)d_in[6];
    const float* outW = (const float*)d_in[7];
    float* logits = (float*)d_out;

    // workspace carve-up (~17.4 MiB)
    char* ws = (char*)d_ws;
    unsigned* bar  = (unsigned*)ws;                               // 16 KiB
    float*    rbuf = (float*)(ws + 16384);                        // 128 KiB
    float*    hbuf = (float*)(ws + 16384 + 131072);               // 512 KiB
    float*    ysf  = (float*)(ws + 16384 + 131072 + 524288);      // 16 MiB

    // 1) zero slot arrays
    bar_init_kernel<<<dim3(1), dim3(1024), 0, stream>>>(bar);

    // 2) MFMA layer-pipelined persistent-weight GRU scan (all-wave barriers)
    gru_scan<<<dim3(SCAN_BLOCKS), dim3(SCAN_THREADS), 0, stream>>>(
        ids, embW, hst, gW, gB, cW, cB, hbuf, rbuf, ysf, bar);

    // 3) logits GEMM
    out_gemm<<<dim3(VOCAB / BN, (NB * SEQ) / BM), dim3(256), 0, stream>>>(ysf, outW, logits);
}